// Round 16
// baseline (85.188 us; speedup 1.0000x reference)
//
#include <hip/hip_runtime.h>
#include <math.h>

typedef float f32x4 __attribute__((ext_vector_type(4)));
typedef short bf16x8 __attribute__((ext_vector_type(8)));

#define N_LBL 128
#define TS 128
#define MAXG 128
#define LBLK 512

constexpr float T_INV = 2.0f;   // 1/T, T=0.5
constexpr float EPSf  = 1e-8f;

__device__ inline float wave_reduce_sum64(float v) {
#pragma unroll
  for (int m = 32; m >= 1; m >>= 1) v += __shfl_xor(v, m, 64);
  return v;
}

__device__ inline unsigned short f2bf(float f) {  // RNE
  unsigned int u = __float_as_uint(f);
  unsigned int r = (u + 0x7FFFu + ((u >> 16) & 1u)) >> 16;
  return (unsigned short)r;
}

// Fused setup. Block 0: label histogram->scan->scatter (runs FIRST, overlaps).
// Blocks 1..n/4: four rows each, one wave per row: inv-norm + fp8 cvt + D=0.
__global__ __launch_bounds__(256) void k_prep(const float* __restrict__ x,
    const int* __restrict__ y, float* __restrict__ invn, float* __restrict__ D,
    unsigned char* __restrict__ xb, float* __restrict__ accum,
    int* __restrict__ offs_g, int* __restrict__ rows, int* __restrict__ rank,
    int n, int d) {
  int t = threadIdx.x;

  if (blockIdx.x == 0) {  // ---- label machinery block (first in dispatch) ----
    __shared__ int hist[N_LBL];
    __shared__ int curs[N_LBL];
    __shared__ int loffs[N_LBL + 1];
    if (t < N_LBL) { hist[t] = 0; curs[t] = 0; }
    if (t == 0) *accum = 0.f;
    __syncthreads();
    for (int i = t; i < n; i += 256) atomicAdd(&hist[y[i]], 1);
    __syncthreads();
    if (t == 0) {
      int acc = 0;
      for (int l = 0; l < N_LBL; ++l) { loffs[l] = acc; acc += hist[l]; }
      loffs[N_LBL] = acc;
    }
    __syncthreads();
    if (t <= N_LBL) offs_g[t] = loffs[t];
    for (int i = t; i < n; i += 256) {
      int g = y[i];
      int pos = atomicAdd(&curs[g], 1);
      rows[loffs[g] + pos] = i;
      rank[i] = pos;
    }
    return;
  }

  int lane = t & 63, wid = t >> 6;
  int row = (blockIdx.x - 1) * 4 + wid;
  if (row >= n) return;
  const float4* xr = (const float4*)(x + (size_t)row * d);
  float ss = 0.f;
  for (int i = lane; i < d / 4; i += 64) {
    float4 v = xr[i];
    ss += v.x * v.x + v.y * v.y + v.z * v.z + v.w * v.w;
    if (xb) {
      int p = __builtin_amdgcn_cvt_pk_fp8_f32(v.x, v.y, 0, false);
      p = __builtin_amdgcn_cvt_pk_fp8_f32(v.z, v.w, p, true);
      *(unsigned int*)(xb + (size_t)row * d + i * 4) = (unsigned int)p;
    }
  }
  ss = wave_reduce_sum64(ss);
  if (lane == 0) {
    invn[row] = 1.0f / fmaxf(sqrtf(ss), EPSf);
    D[row] = 0.f;
  }
}

// Shared epilogue. C/D frag layout col=lane&15, row=(lane>>4)*4+r.
// sym=true: off-diagonal tile (also scatter col-sums + symmetric S writes).
__device__ inline void gram_epilogue(const f32x4 acc[4][4], int rowBase,
    int colBase, const float* ir, const float* ic, const int* yr,
    const int* yc, const int* rr, const int* rc, bool sym,
    float* __restrict__ D, float* __restrict__ S,
    int wr, int wc, int l15, int l4) {
  float cs[4] = {0.f, 0.f, 0.f, 0.f};
#pragma unroll
  for (int m = 0; m < 4; ++m) {
#pragma unroll
    for (int r = 0; r < 4; ++r) {
      int lr = wr * 64 + m * 16 + l4 * 4 + r;
      int gi = rowBase + lr;
      float ivr = ir[lr];
      int yi = yr[lr];
      float rs = 0.f;
#pragma unroll
      for (int nn = 0; nn < 4; ++nn) {
        int lc = wc * 64 + nn * 16 + l15;
        int gj = colBase + lc;
        float sim = acc[m][nn][r] * ivr * ic[lc];
        sim = fminf(fmaxf(sim, -1.0f + EPSf), 1.0f - EPSf);
        float s = fminf(__expf(sim * T_INV), 1e10f);
        if (yc[lc] != yi) {
          rs += s; cs[nn] += s;
        } else if (gi != gj) {
          S[(size_t)gi * MAXG + rc[lc]] = s;
          if (sym) S[(size_t)gj * MAXG + rr[lr]] = s;
        }
      }
      rs += __shfl_xor(rs, 1, 64);
      rs += __shfl_xor(rs, 2, 64);
      rs += __shfl_xor(rs, 4, 64);
      rs += __shfl_xor(rs, 8, 64);
      if (l15 == 0) atomicAdd(&D[gi], rs);
    }
  }
  if (sym) {
#pragma unroll
    for (int nn = 0; nn < 4; ++nn) {
      float v = cs[nn];
      v += __shfl_xor(v, 16, 64);
      v += __shfl_xor(v, 32, 64);
      if (l4 == 0) atomicAdd(&D[colBase + wc * 64 + nn * 16 + l15], v);
    }
  }
}

// ---------------- Gram pass, fast path: fp8, uniform 512-block grid -------
// nwg = nb(nb-1)/2 + nb/2. Every nb-th bid (slot nb-1) is a "diag-pair"
// block: stages A-panels of diagonal tiles (2g,2g) into ldsA and (2g+1,2g+1)
// into ldsB each K-step and computes BOTH tiles concurrently (acc0, acc1).
// All blocks: 8 K-steps x 32 KB staged -> perfectly uniform bytes AND serial
// depth; diag-pairs interleave 2-per-XCD-chunk. XOR swizzle on per-lane
// GLOBAL source; LDS dest linear. MFMA: f32_16x16x32_fp8_fp8.
__global__ __launch_bounds__(256) void k_gram_ldsdma(
    const unsigned char* __restrict__ xb, const float* __restrict__ invn,
    const int* __restrict__ y, const int* __restrict__ rank,
    float* __restrict__ D, float* __restrict__ S, int n, int d, int nb) {
  int nwg = nb * (nb - 1) / 2 + nb / 2;
  // bijective XCD-chunked remap (m204)
  int q8 = nwg >> 3, r8 = nwg & 7;
  int xcd = blockIdx.x & 7, ridx = blockIdx.x >> 3;
  int bid = (xcd < r8 ? xcd * (q8 + 1) : r8 * (q8 + 1) + (xcd - r8) * q8) + ridx;

  int grp = bid / nb, slot = bid % nb;
  bool diag = (slot == nb - 1);
  int by, bx;
  if (!diag) {
    int off_idx = grp * (nb - 1) + slot;       // 0 .. nb(nb-1)/2 - 1
    int b = 0, rowlen = nb - 1, rem = off_idx; // strict upper triangle
    while (rem >= rowlen) { rem -= rowlen; ++b; --rowlen; }
    by = b; bx = b + 1 + rem;
  } else {
    by = 2 * grp; bx = 2 * grp + 1;            // two diagonal tiles
  }
  int rowBase = by * TS, colBase = bx * TS;

  __shared__ char ldsA[128 * 128];   // 16 KB
  __shared__ char ldsB[128 * 128];   // 16 KB
  __shared__ float ir_s[128], ic_s[128];
  __shared__ int yr_s[128], yc_s[128];
  __shared__ int rr_s[128], rc_s[128];

  int t = threadIdx.x;
  int lane = t & 63, wid = t >> 6;
  int wr = wid >> 1, wc = wid & 1;          // 2x2 wave grid, 64x64 per wave
  int l15 = lane & 15, l4 = lane >> 4;
  int lrow = lane >> 3, lp = lane & 7;      // staging: row-in-8 / 16B chunk

  if (t < 128) {
    ir_s[t] = invn[rowBase + t]; yr_s[t] = y[rowBase + t]; rr_s[t] = rank[rowBase + t];
    ic_s[t] = invn[colBase + t]; yc_s[t] = y[colBase + t]; rc_s[t] = rank[colBase + t];
  }

  f32x4 acc0[4][4], acc1[4][4];
#pragma unroll
  for (int m = 0; m < 4; ++m)
#pragma unroll
    for (int nn = 0; nn < 4; ++nn) {
      acc0[m][nn] = (f32x4){0.f, 0.f, 0.f, 0.f};
      acc1[m][nn] = (f32x4){0.f, 0.f, 0.f, 0.f};
    }

  int nt = d / 128;     // 8 K-steps

  for (int g = 0; g < nt; ++g) {
    __syncthreads();    // prev compute done: safe to overwrite panels
    // stage both panels: 2 x 128 rows x 128 B (1 KB per wave-instr = 8 rows)
#pragma unroll
    for (int j = 0; j < 4; ++j) {
      int seg = wid * 4 + j;                // 0..15, 8 rows each
      int row = seg * 8 + lrow;
      int swz = (lp ^ (row & 7)) << 4;
      const unsigned char* srcA = xb + (size_t)(rowBase + row) * d + g * 128 + swz;
      __builtin_amdgcn_global_load_lds(
          (const __attribute__((address_space(1))) void*)srcA,
          (__attribute__((address_space(3))) void*)(ldsA + seg * 1024), 16, 0, 0);
      const unsigned char* srcB = xb + (size_t)(colBase + row) * d + g * 128 + swz;
      __builtin_amdgcn_global_load_lds(
          (const __attribute__((address_space(1))) void*)srcB,
          (__attribute__((address_space(3))) void*)(ldsB + seg * 1024), 16, 0, 0);
    }
    __syncthreads();    // drain: panels resident

#pragma unroll
    for (int kk = 0; kk < 4; ++kk) {        // 4 x K=32 per panel
      long a0[4], b0[4];
#pragma unroll
      for (int m = 0; m < 4; ++m) {
        int row = wr * 64 + m * 16 + l15;
        int sl = (kk * 2 + (l4 >> 1)) ^ (row & 7);
        a0[m] = *(const long*)(ldsA + row * 128 + sl * 16 + (l4 & 1) * 8);
      }
      if (!diag) {
#pragma unroll
        for (int nn = 0; nn < 4; ++nn) {
          int row = wc * 64 + nn * 16 + l15;
          int sl = (kk * 2 + (l4 >> 1)) ^ (row & 7);
          b0[nn] = *(const long*)(ldsB + row * 128 + sl * 16 + (l4 & 1) * 8);
        }
#pragma unroll
        for (int m = 0; m < 4; ++m)
#pragma unroll
          for (int nn = 0; nn < 4; ++nn)
            acc0[m][nn] = __builtin_amdgcn_mfma_f32_16x16x32_fp8_fp8(a0[m], b0[nn], acc0[m][nn], 0, 0, 0);
      } else {
        long a1[4], b1[4];
#pragma unroll
        for (int nn = 0; nn < 4; ++nn) {
          int row = wc * 64 + nn * 16 + l15;
          int sl = (kk * 2 + (l4 >> 1)) ^ (row & 7);
          b0[nn] = *(const long*)(ldsA + row * 128 + sl * 16 + (l4 & 1) * 8);
          b1[nn] = *(const long*)(ldsB + row * 128 + sl * 16 + (l4 & 1) * 8);
        }
#pragma unroll
        for (int m = 0; m < 4; ++m) {
          int row = wr * 64 + m * 16 + l15;
          int sl = (kk * 2 + (l4 >> 1)) ^ (row & 7);
          a1[m] = *(const long*)(ldsB + row * 128 + sl * 16 + (l4 & 1) * 8);
        }
#pragma unroll
        for (int m = 0; m < 4; ++m)
#pragma unroll
          for (int nn = 0; nn < 4; ++nn) {
            acc0[m][nn] = __builtin_amdgcn_mfma_f32_16x16x32_fp8_fp8(a0[m], b0[nn], acc0[m][nn], 0, 0, 0);
            acc1[m][nn] = __builtin_amdgcn_mfma_f32_16x16x32_fp8_fp8(a1[m], b1[nn], acc1[m][nn], 0, 0, 0);
          }
      }
    }
  }

  if (!diag) {
    gram_epilogue(acc0, rowBase, colBase, ir_s, ic_s, yr_s, yc_s, rr_s, rc_s,
                  true, D, S, wr, wc, l15, l4);
  } else {
    gram_epilogue(acc0, rowBase, rowBase, ir_s, ir_s, yr_s, yr_s, rr_s, rr_s,
                  false, D, S, wr, wc, l15, l4);
    gram_epilogue(acc1, colBase, colBase, ic_s, ic_s, yc_s, yc_s, rc_s, rc_s,
                  false, D, S, wr, wc, l15, l4);
  }
}

// ---------------- Gram pass, fallback: reg-staged f32->bf16 ---------------
__global__ __launch_bounds__(256) void k_gram_reg(const float* __restrict__ x,
    const float* __restrict__ invn, const int* __restrict__ y,
    const int* __restrict__ rank, float* __restrict__ D, float* __restrict__ S,
    int n, int d, int nb) {
  int bid = blockIdx.x;
  int by = 0, rowlen = nb, rem = bid;
  while (rem >= rowlen) { rem -= rowlen; ++by; --rowlen; }
  int bx = by + rem;
  int rowBase = by * TS, colBase = bx * TS;
  bool diag = (bx == by);

  __shared__ char ldsA[128 * 128];
  __shared__ char ldsB[128 * 128];
  __shared__ float ir_s[128], ic_s[128];
  __shared__ int yr_s[128], yc_s[128];
  __shared__ int rr_s[128], rc_s[128];

  int t = threadIdx.x;
  int lane = t & 63, wid = t >> 6;
  int wr = wid >> 1, wc = wid & 1;
  int l15 = lane & 15, l4 = lane >> 4;

  if (t < 128) {
    ir_s[t] = invn[rowBase + t]; yr_s[t] = y[rowBase + t]; rr_s[t] = rank[rowBase + t];
    ic_s[t] = invn[colBase + t]; yc_s[t] = y[colBase + t]; rc_s[t] = rank[colBase + t];
  }

  f32x4 acc[4][4];
#pragma unroll
  for (int m = 0; m < 4; ++m)
#pragma unroll
    for (int nn = 0; nn < 4; ++nn) acc[m][nn] = (f32x4){0.f, 0.f, 0.f, 0.f};

  const char* ldsBr = diag ? ldsA : ldsB;

  for (int k0 = 0; k0 < d; k0 += 64) {
    __syncthreads();
#pragma unroll
    for (int i = 0; i < 8; ++i) {
      int c = t + i * 256;
      int row = c >> 4, fc = c & 15;
      float4 v = *(const float4*)(x + (size_t)(rowBase + row) * d + k0 + fc * 4);
      ushort4 hh;
      hh.x = f2bf(v.x); hh.y = f2bf(v.y); hh.z = f2bf(v.z); hh.w = f2bf(v.w);
      int off = row * 128 + ((((fc >> 1) ^ (row & 7))) << 4) + (fc & 1) * 8;
      *(ushort4*)(ldsA + off) = hh;
    }
    if (!diag) {
#pragma unroll
      for (int i = 0; i < 8; ++i) {
        int c = t + i * 256;
        int row = c >> 4, fc = c & 15;
        float4 v = *(const float4*)(x + (size_t)(colBase + row) * d + k0 + fc * 4);
        ushort4 hh;
        hh.x = f2bf(v.x); hh.y = f2bf(v.y); hh.z = f2bf(v.z); hh.w = f2bf(v.w);
        int off = row * 128 + ((((fc >> 1) ^ (row & 7))) << 4) + (fc & 1) * 8;
        *(ushort4*)(ldsB + off) = hh;
      }
    }
    __syncthreads();

#pragma unroll
    for (int kk = 0; kk < 2; ++kk) {
      bf16x8 a[4], b[4];
#pragma unroll
      for (int m = 0; m < 4; ++m) {
        int row = wr * 64 + m * 16 + l15;
        int slot = (kk * 4 + l4) ^ (row & 7);
        a[m] = *(const bf16x8*)(ldsA + row * 128 + slot * 16);
      }
#pragma unroll
      for (int nn = 0; nn < 4; ++nn) {
        int row = wc * 64 + nn * 16 + l15;
        int slot = (kk * 4 + l4) ^ (row & 7);
        b[nn] = *(const bf16x8*)(ldsBr + row * 128 + slot * 16);
      }
#pragma unroll
      for (int m = 0; m < 4; ++m)
#pragma unroll
        for (int nn = 0; nn < 4; ++nn)
          acc[m][nn] = __builtin_amdgcn_mfma_f32_16x16x32_bf16(a[m], b[nn], acc[m][nn], 0, 0, 0);
    }
  }

  float cs[4] = {0.f, 0.f, 0.f, 0.f};
#pragma unroll
  for (int m = 0; m < 4; ++m) {
#pragma unroll
    for (int r = 0; r < 4; ++r) {
      int lr = wr * 64 + m * 16 + l4 * 4 + r;
      int gi = rowBase + lr;
      float ivr = ir_s[lr];
      int yi = yr_s[lr];
      float rs = 0.f;
#pragma unroll
      for (int nn = 0; nn < 4; ++nn) {
        int lc = wc * 64 + nn * 16 + l15;
        int gj = colBase + lc;
        float sim = acc[m][nn][r] * ivr * ic_s[lc];
        sim = fminf(fmaxf(sim, -1.0f + EPSf), 1.0f - EPSf);
        float s = fminf(__expf(sim * T_INV), 1e10f);
        if (yc_s[lc] != yi) {
          rs += s; cs[nn] += s;
        } else if (S && gi != gj) {
          S[(size_t)gi * MAXG + rc_s[lc]] = s;
          if (!diag) S[(size_t)gj * MAXG + rr_s[lr]] = s;
        }
      }
      rs += __shfl_xor(rs, 1, 64);
      rs += __shfl_xor(rs, 2, 64);
      rs += __shfl_xor(rs, 4, 64);
      rs += __shfl_xor(rs, 8, 64);
      if (l15 == 0) atomicAdd(&D[rowBase + lr], rs);
    }
  }
  if (!diag) {
#pragma unroll
    for (int nn = 0; nn < 4; ++nn) {
      float v = cs[nn];
      v += __shfl_xor(v, 16, 64);
      v += __shfl_xor(v, 32, 64);
      if (l4 == 0) atomicAdd(&D[colBase + wc * 64 + nn * 16 + l15], v);
    }
  }
}

// Pass B (fast): grid-strided; per-block partial sums, no global atomics.
__global__ __launch_bounds__(256) void k_loss2(const int* __restrict__ y,
    const int* __restrict__ offs, const int* __restrict__ rows,
    const float* __restrict__ D, const float* __restrict__ S,
    float* __restrict__ partials, int n) {
  int t = threadIdx.x;
  int total = n * MAXG;
  float sum = 0.f;
  for (int gid = blockIdx.x * 256 + t; gid < total; gid += gridDim.x * 256) {
    int i = gid >> 7;          // MAXG = 128
    int slot = gid & (MAXG - 1);
    int g = y[i];
    int start = offs[g], cnt = offs[g + 1] - start;
    if (slot < cnt) {
      int j = rows[start + slot];
      if (j != i) {
        float s = S[(size_t)i * MAXG + slot];
        sum += logf(s + D[i] + EPSf) - logf(s);
      }
    }
  }
  sum = wave_reduce_sum64(sum);
  __shared__ float part[4];
  int lane = t & 63, wid = t >> 6;
  if (lane == 0) part[wid] = sum;
  __syncthreads();
  if (t == 0) partials[blockIdx.x] = part[0] + part[1] + part[2] + part[3];
}

// Pass B (fallback): recompute dots for same-label pairs
__global__ __launch_bounds__(256) void k_loss(const float* __restrict__ x,
    const float* __restrict__ invn, const int* __restrict__ y,
    const int* __restrict__ offs, const int* __restrict__ rows,
    const float* __restrict__ D, float* __restrict__ accum, int n, int d) {
  int i = blockIdx.x;
  int t = threadIdx.x, lane = t & 63, wid = t >> 6;
  __shared__ float4 xi4[256];
  __shared__ float wpart[4];

  const float4* xr = (const float4*)(x + (size_t)i * d);
  for (int q = t; q < d / 4; q += 256) xi4[q] = xr[q];
  __syncthreads();

  int g = y[i];
  int start = offs[g], end = offs[g + 1];
  float invi = invn[i];
  float Di = D[i];
  float wsum = 0.f;

  for (int idx = start + wid; idx < end; idx += 4) {
    int j = rows[idx];
    if (j == i) continue;
    const float4* xj = (const float4*)(x + (size_t)j * d);
    float acc = 0.f;
#pragma unroll 4
    for (int q = 0; q < d / 256; ++q) {
      float4 vj = xj[lane + 64 * q];
      float4 vi = xi4[lane + 64 * q];
      acc = fmaf(vj.x, vi.x, acc);
      acc = fmaf(vj.y, vi.y, acc);
      acc = fmaf(vj.z, vi.z, acc);
      acc = fmaf(vj.w, vi.w, acc);
    }
    acc = wave_reduce_sum64(acc);
    if (lane == 0) {
      float sim = acc * invi * invn[j];
      sim = fminf(fmaxf(sim, -1.0f + EPSf), 1.0f - EPSf);
      float s = fminf(expf(sim * T_INV), 1e10f);
      wsum += logf(s + Di + EPSf) - logf(s);
    }
  }

  if (lane == 0) wpart[wid] = wsum;
  __syncthreads();
  if (t == 0) atomicAdd(accum, wpart[0] + wpart[1] + wpart[2] + wpart[3]);
}

// Final reduce: sums `cnt` partials, writes out/(2n).
__global__ __launch_bounds__(256) void k_final(const float* __restrict__ partials,
    int cnt, float* __restrict__ out, int out_size, int n) {
  int t = threadIdx.x;
  float s = 0.f;
  for (int i = t; i < cnt; i += 256) s += partials[i];
  s = wave_reduce_sum64(s);
  __shared__ float part[4];
  int lane = t & 63, wid = t >> 6;
  if (lane == 0) part[wid] = s;
  __syncthreads();
  if (t == 0) {
    float v = part[0] + part[1] + part[2] + part[3];
    for (int k = 0; k < out_size; ++k) out[k] = v / (2.0f * n);
  }
}

extern "C" void kernel_launch(void* const* d_in, const int* in_sizes, int n_in,
                              void* d_out, int out_size, void* d_ws, size_t ws_size,
                              hipStream_t stream) {
  const float* x = (const float*)d_in[0];
  const int*   y = (const int*)d_in[1];
  int n = in_sizes[1];
  int d = in_sizes[0] / n;

  char* ws = (char*)d_ws;
  float* invn     = (float*)(ws);            // 16 KB
  float* D        = (float*)(ws + 16384);    // 16 KB
  int*   offs     = (int*)(ws + 32768);      // 129 ints (pad to 2 KB)
  int*   rows     = (int*)(ws + 34816);      // 16 KB
  int*   rank     = (int*)(ws + 51200);      // 16 KB
  float* accum    = (float*)(ws + 67584);    // 4 B (pad 256 B)
  float* partials = (float*)(ws + 67840);    // LBLK floats (2 KB)
  float* S        = (float*)(ws + 69888);    // n*MAXG*4 = 2 MB
  size_t xb_off = 69888 + (size_t)n * MAXG * 4;
  xb_off = (xb_off + 255) & ~(size_t)255;
  unsigned char* xb = (unsigned char*)(ws + xb_off);   // n*d fp8 = 4 MB

  int nb = n / TS;
  bool hasS  = ws_size >= 69888 + (size_t)n * MAXG * 4;
  bool hasXb = hasS && ws_size >= xb_off + (size_t)n * d
               && (d % 128 == 0) && (nb % 2 == 0) && (n % 4 == 0);

  k_prep<<<n / 4 + 1, 256, 0, stream>>>(x, y, invn, D, hasXb ? xb : nullptr,
                                        accum, offs, rows, rank, n, d);

  if (hasXb) {
    int nblocks = nb * (nb - 1) / 2 + nb / 2;   // 496 + 16 = 512 at n=4096
    k_gram_ldsdma<<<nblocks, 256, 0, stream>>>(xb, invn, y, rank, D, S, n, d, nb);
  } else {
    int nblocks = nb * (nb + 1) / 2;
    k_gram_reg<<<nblocks, 256, 0, stream>>>(x, invn, y, rank, D, hasS ? S : nullptr, n, d, nb);
  }
  if (hasS) {
    k_loss2<<<LBLK, 256, 0, stream>>>(y, offs, rows, D, S, partials, n);
    k_final<<<1, 256, 0, stream>>>(partials, LBLK, (float*)d_out, out_size, n);
  } else {
    k_loss<<<n, 256, 0, stream>>>(x, invn, y, offs, rows, D, accum, n, d);
    k_final<<<1, 256, 0, stream>>>(accum, 1, (float*)d_out, out_size, n);
  }
}

// Round 17
// 49.843 us; speedup vs baseline: 1.7091x; 1.7091x over previous
//
#include <hip/hip_runtime.h>
#include <math.h>

typedef float f32x4 __attribute__((ext_vector_type(4)));
typedef short bf16x8 __attribute__((ext_vector_type(8)));

#define N_LBL 128
#define TS 128
#define MAXG 128
#define LBLK 512

constexpr float T_INV = 2.0f;   // 1/T, T=0.5
constexpr float EPSf  = 1e-8f;

__device__ inline float wave_reduce_sum64(float v) {
#pragma unroll
  for (int m = 32; m >= 1; m >>= 1) v += __shfl_xor(v, m, 64);
  return v;
}

__device__ inline unsigned short f2bf(float f) {  // RNE
  unsigned int u = __float_as_uint(f);
  unsigned int r = (u + 0x7FFFu + ((u >> 16) & 1u)) >> 16;
  return (unsigned short)r;
}

// Fused setup. Block 0: label histogram->scan->scatter (runs FIRST, overlaps).
// Blocks 1..n/4: four rows each, one wave per row: inv-norm + fp8 cvt + D=0.
__global__ __launch_bounds__(256) void k_prep(const float* __restrict__ x,
    const int* __restrict__ y, float* __restrict__ invn, float* __restrict__ D,
    unsigned char* __restrict__ xb, float* __restrict__ accum,
    int* __restrict__ offs_g, int* __restrict__ rows, int* __restrict__ rank,
    int n, int d) {
  int t = threadIdx.x;

  if (blockIdx.x == 0) {  // ---- label machinery block (first in dispatch) ----
    __shared__ int hist[N_LBL];
    __shared__ int curs[N_LBL];
    __shared__ int loffs[N_LBL + 1];
    if (t < N_LBL) { hist[t] = 0; curs[t] = 0; }
    if (t == 0) *accum = 0.f;
    __syncthreads();
    for (int i = t; i < n; i += 256) atomicAdd(&hist[y[i]], 1);
    __syncthreads();
    if (t == 0) {
      int acc = 0;
      for (int l = 0; l < N_LBL; ++l) { loffs[l] = acc; acc += hist[l]; }
      loffs[N_LBL] = acc;
    }
    __syncthreads();
    if (t <= N_LBL) offs_g[t] = loffs[t];
    for (int i = t; i < n; i += 256) {
      int g = y[i];
      int pos = atomicAdd(&curs[g], 1);
      rows[loffs[g] + pos] = i;
      rank[i] = pos;
    }
    return;
  }

  int lane = t & 63, wid = t >> 6;
  int row = (blockIdx.x - 1) * 4 + wid;
  if (row >= n) return;
  const float4* xr = (const float4*)(x + (size_t)row * d);
  float ss = 0.f;
  for (int i = lane; i < d / 4; i += 64) {
    float4 v = xr[i];
    ss += v.x * v.x + v.y * v.y + v.z * v.z + v.w * v.w;
    if (xb) {
      int p = __builtin_amdgcn_cvt_pk_fp8_f32(v.x, v.y, 0, false);
      p = __builtin_amdgcn_cvt_pk_fp8_f32(v.z, v.w, p, true);
      *(unsigned int*)(xb + (size_t)row * d + i * 4) = (unsigned int)p;
    }
  }
  ss = wave_reduce_sum64(ss);
  if (lane == 0) {
    invn[row] = 1.0f / fmaxf(sqrtf(ss), EPSf);
    D[row] = 0.f;
  }
}

// ---------------- Gram pass, fast path: fp8, BK=128, diag-last grid -------
// blockIdx 0..noff-1: off-diagonal tiles (XCD-swizzled; 496 = 8x62 exact).
// blockIdx noff..noff+nb-1: diagonal tiles, dispatched LAST -> greedy
// shortest-last scheduling fills earliest-free CUs (they cost ~0.6T: A-only
// staging, same MFMA). 256 threads (4 waves, 2x2 grid; 64x64/wave).
// LDS panel: 128 rows x 128 fp8, XOR swizzle on per-lane GLOBAL source,
// LDS dest linear. MFMA: f32_16x16x32_fp8_fp8. Single acc[4][4], VGPR ~108.
__global__ __launch_bounds__(256) void k_gram_ldsdma(
    const unsigned char* __restrict__ xb, const float* __restrict__ invn,
    const int* __restrict__ y, const int* __restrict__ rank,
    float* __restrict__ D, float* __restrict__ S, int n, int d, int nb) {
  int noff = nb * (nb - 1) / 2;
  int by, bx;
  if ((int)blockIdx.x < noff) {
    // bijective XCD-chunked remap (m204) over off-diag tiles only
    int q8 = noff >> 3, r8 = noff & 7;
    int xcd = blockIdx.x & 7, ridx = blockIdx.x >> 3;
    int bid = (xcd < r8 ? xcd * (q8 + 1) : r8 * (q8 + 1) + (xcd - r8) * q8) + ridx;
    int b = 0, rowlen = nb - 1, rem = bid;   // strict upper triangle
    while (rem >= rowlen) { rem -= rowlen; ++b; --rowlen; }
    by = b; bx = b + 1 + rem;
  } else {
    by = bx = blockIdx.x - noff;             // diagonal tiles, last
  }
  int rowBase = by * TS, colBase = bx * TS;
  bool diag = (bx == by);

  __shared__ char ldsA[128 * 128];   // 16 KB
  __shared__ char ldsB[128 * 128];   // 16 KB
  __shared__ float ir_s[128], ic_s[128];
  __shared__ int yr_s[128], yc_s[128];
  __shared__ int rr_s[128], rc_s[128];

  int t = threadIdx.x;
  int lane = t & 63, wid = t >> 6;
  int wr = wid >> 1, wc = wid & 1;          // 2x2 wave grid, 64x64 per wave
  int l15 = lane & 15, l4 = lane >> 4;
  int lrow = lane >> 3, lp = lane & 7;      // staging: row-in-8 / 16B chunk

  if (t < 128) {
    ir_s[t] = invn[rowBase + t]; yr_s[t] = y[rowBase + t]; rr_s[t] = rank[rowBase + t];
    ic_s[t] = invn[colBase + t]; yc_s[t] = y[colBase + t]; rc_s[t] = rank[colBase + t];
  }

  f32x4 acc[4][4];
#pragma unroll
  for (int m = 0; m < 4; ++m)
#pragma unroll
    for (int nn = 0; nn < 4; ++nn) acc[m][nn] = (f32x4){0.f, 0.f, 0.f, 0.f};

  const char* ldsBr = diag ? ldsA : ldsB;
  int nt = d / 128;     // 8 K-steps

  for (int g = 0; g < nt; ++g) {
    __syncthreads();    // prev compute done: safe to overwrite panels
    // stage: 128 rows x 128 B; each wave-instr writes 1 KB = 8 rows.
#pragma unroll
    for (int j = 0; j < 4; ++j) {
      int seg = wid * 4 + j;                // 0..15, 8 rows each
      int row = seg * 8 + lrow;
      const unsigned char* srcA = xb + (size_t)(rowBase + row) * d + g * 128
                                  + ((lp ^ (row & 7)) << 4);
      __builtin_amdgcn_global_load_lds(
          (const __attribute__((address_space(1))) void*)srcA,
          (__attribute__((address_space(3))) void*)(ldsA + seg * 1024), 16, 0, 0);
    }
    if (!diag) {
#pragma unroll
      for (int j = 0; j < 4; ++j) {
        int seg = wid * 4 + j;
        int row = seg * 8 + lrow;
        const unsigned char* srcB = xb + (size_t)(colBase + row) * d + g * 128
                                    + ((lp ^ (row & 7)) << 4);
        __builtin_amdgcn_global_load_lds(
            (const __attribute__((address_space(1))) void*)srcB,
            (__attribute__((address_space(3))) void*)(ldsB + seg * 1024), 16, 0, 0);
      }
    }
    __syncthreads();    // drain: tile resident

#pragma unroll
    for (int kk = 0; kk < 4; ++kk) {        // 4 x K=32 per panel
      long a[4], b[4];
#pragma unroll
      for (int m = 0; m < 4; ++m) {
        int row = wr * 64 + m * 16 + l15;
        int slot = (kk * 2 + (l4 >> 1)) ^ (row & 7);
        a[m] = *(const long*)(ldsA + row * 128 + slot * 16 + (l4 & 1) * 8);
      }
#pragma unroll
      for (int nn = 0; nn < 4; ++nn) {
        int row = wc * 64 + nn * 16 + l15;
        int slot = (kk * 2 + (l4 >> 1)) ^ (row & 7);
        b[nn] = *(const long*)(ldsBr + row * 128 + slot * 16 + (l4 & 1) * 8);
      }
#pragma unroll
      for (int m = 0; m < 4; ++m)
#pragma unroll
        for (int nn = 0; nn < 4; ++nn)
          acc[m][nn] = __builtin_amdgcn_mfma_f32_16x16x32_fp8_fp8(a[m], b[nn], acc[m][nn], 0, 0, 0);
    }
  }

  // epilogue (inline): C/D frag layout col=lane&15, row=(lane>>4)*4+r
  float cs[4] = {0.f, 0.f, 0.f, 0.f};
#pragma unroll
  for (int m = 0; m < 4; ++m) {
#pragma unroll
    for (int r = 0; r < 4; ++r) {
      int lr = wr * 64 + m * 16 + l4 * 4 + r;
      int gi = rowBase + lr;
      float ivr = ir_s[lr];
      int yi = yr_s[lr];
      float rs = 0.f;
#pragma unroll
      for (int nn = 0; nn < 4; ++nn) {
        int lc = wc * 64 + nn * 16 + l15;
        int gj = colBase + lc;
        float sim = acc[m][nn][r] * ivr * ic_s[lc];
        sim = fminf(fmaxf(sim, -1.0f + EPSf), 1.0f - EPSf);
        float s = fminf(__expf(sim * T_INV), 1e10f);
        if (yc_s[lc] != yi) {
          rs += s; cs[nn] += s;
        } else if (gi != gj) {
          S[(size_t)gi * MAXG + rc_s[lc]] = s;
          if (!diag) S[(size_t)gj * MAXG + rr_s[lr]] = s;
        }
      }
      rs += __shfl_xor(rs, 1, 64);
      rs += __shfl_xor(rs, 2, 64);
      rs += __shfl_xor(rs, 4, 64);
      rs += __shfl_xor(rs, 8, 64);
      if (l15 == 0) atomicAdd(&D[rowBase + lr], rs);
    }
  }
  if (!diag) {
#pragma unroll
    for (int nn = 0; nn < 4; ++nn) {
      float v = cs[nn];
      v += __shfl_xor(v, 16, 64);
      v += __shfl_xor(v, 32, 64);
      if (l4 == 0) atomicAdd(&D[colBase + wc * 64 + nn * 16 + l15], v);
    }
  }
}

// ---------------- Gram pass, fallback: reg-staged f32->bf16 ---------------
__global__ __launch_bounds__(256) void k_gram_reg(const float* __restrict__ x,
    const float* __restrict__ invn, const int* __restrict__ y,
    const int* __restrict__ rank, float* __restrict__ D, float* __restrict__ S,
    int n, int d, int nb) {
  int bid = blockIdx.x;
  int by = 0, rowlen = nb, rem = bid;
  while (rem >= rowlen) { rem -= rowlen; ++by; --rowlen; }
  int bx = by + rem;
  int rowBase = by * TS, colBase = bx * TS;
  bool diag = (bx == by);

  __shared__ char ldsA[128 * 128];
  __shared__ char ldsB[128 * 128];
  __shared__ float ir_s[128], ic_s[128];
  __shared__ int yr_s[128], yc_s[128];
  __shared__ int rr_s[128], rc_s[128];

  int t = threadIdx.x;
  int lane = t & 63, wid = t >> 6;
  int wr = wid >> 1, wc = wid & 1;
  int l15 = lane & 15, l4 = lane >> 4;

  if (t < 128) {
    ir_s[t] = invn[rowBase + t]; yr_s[t] = y[rowBase + t]; rr_s[t] = rank[rowBase + t];
    ic_s[t] = invn[colBase + t]; yc_s[t] = y[colBase + t]; rc_s[t] = rank[colBase + t];
  }

  f32x4 acc[4][4];
#pragma unroll
  for (int m = 0; m < 4; ++m)
#pragma unroll
    for (int nn = 0; nn < 4; ++nn) acc[m][nn] = (f32x4){0.f, 0.f, 0.f, 0.f};

  const char* ldsBr = diag ? ldsA : ldsB;

  for (int k0 = 0; k0 < d; k0 += 64) {
    __syncthreads();
#pragma unroll
    for (int i = 0; i < 8; ++i) {
      int c = t + i * 256;
      int row = c >> 4, fc = c & 15;
      float4 v = *(const float4*)(x + (size_t)(rowBase + row) * d + k0 + fc * 4);
      ushort4 hh;
      hh.x = f2bf(v.x); hh.y = f2bf(v.y); hh.z = f2bf(v.z); hh.w = f2bf(v.w);
      int off = row * 128 + ((((fc >> 1) ^ (row & 7))) << 4) + (fc & 1) * 8;
      *(ushort4*)(ldsA + off) = hh;
    }
    if (!diag) {
#pragma unroll
      for (int i = 0; i < 8; ++i) {
        int c = t + i * 256;
        int row = c >> 4, fc = c & 15;
        float4 v = *(const float4*)(x + (size_t)(colBase + row) * d + k0 + fc * 4);
        ushort4 hh;
        hh.x = f2bf(v.x); hh.y = f2bf(v.y); hh.z = f2bf(v.z); hh.w = f2bf(v.w);
        int off = row * 128 + ((((fc >> 1) ^ (row & 7))) << 4) + (fc & 1) * 8;
        *(ushort4*)(ldsB + off) = hh;
      }
    }
    __syncthreads();

#pragma unroll
    for (int kk = 0; kk < 2; ++kk) {
      bf16x8 a[4], b[4];
#pragma unroll
      for (int m = 0; m < 4; ++m) {
        int row = wr * 64 + m * 16 + l15;
        int slot = (kk * 4 + l4) ^ (row & 7);
        a[m] = *(const bf16x8*)(ldsA + row * 128 + slot * 16);
      }
#pragma unroll
      for (int nn = 0; nn < 4; ++nn) {
        int row = wc * 64 + nn * 16 + l15;
        int slot = (kk * 4 + l4) ^ (row & 7);
        b[nn] = *(const bf16x8*)(ldsBr + row * 128 + slot * 16);
      }
#pragma unroll
      for (int m = 0; m < 4; ++m)
#pragma unroll
        for (int nn = 0; nn < 4; ++nn)
          acc[m][nn] = __builtin_amdgcn_mfma_f32_16x16x32_bf16(a[m], b[nn], acc[m][nn], 0, 0, 0);
    }
  }

  float cs[4] = {0.f, 0.f, 0.f, 0.f};
#pragma unroll
  for (int m = 0; m < 4; ++m) {
#pragma unroll
    for (int r = 0; r < 4; ++r) {
      int lr = wr * 64 + m * 16 + l4 * 4 + r;
      int gi = rowBase + lr;
      float ivr = ir_s[lr];
      int yi = yr_s[lr];
      float rs = 0.f;
#pragma unroll
      for (int nn = 0; nn < 4; ++nn) {
        int lc = wc * 64 + nn * 16 + l15;
        int gj = colBase + lc;
        float sim = acc[m][nn][r] * ivr * ic_s[lc];
        sim = fminf(fmaxf(sim, -1.0f + EPSf), 1.0f - EPSf);
        float s = fminf(__expf(sim * T_INV), 1e10f);
        if (yc_s[lc] != yi) {
          rs += s; cs[nn] += s;
        } else if (S && gi != gj) {
          S[(size_t)gi * MAXG + rc_s[lc]] = s;
          if (!diag) S[(size_t)gj * MAXG + rr_s[lr]] = s;
        }
      }
      rs += __shfl_xor(rs, 1, 64);
      rs += __shfl_xor(rs, 2, 64);
      rs += __shfl_xor(rs, 4, 64);
      rs += __shfl_xor(rs, 8, 64);
      if (l15 == 0) atomicAdd(&D[rowBase + lr], rs);
    }
  }
  if (!diag) {
#pragma unroll
    for (int nn = 0; nn < 4; ++nn) {
      float v = cs[nn];
      v += __shfl_xor(v, 16, 64);
      v += __shfl_xor(v, 32, 64);
      if (l4 == 0) atomicAdd(&D[colBase + wc * 64 + nn * 16 + l15], v);
    }
  }
}

// Pass B (fast): grid-strided; per-block partial sums, no global atomics.
__global__ __launch_bounds__(256) void k_loss2(const int* __restrict__ y,
    const int* __restrict__ offs, const int* __restrict__ rows,
    const float* __restrict__ D, const float* __restrict__ S,
    float* __restrict__ partials, int n) {
  int t = threadIdx.x;
  int total = n * MAXG;
  float sum = 0.f;
  for (int gid = blockIdx.x * 256 + t; gid < total; gid += gridDim.x * 256) {
    int i = gid >> 7;          // MAXG = 128
    int slot = gid & (MAXG - 1);
    int g = y[i];
    int start = offs[g], cnt = offs[g + 1] - start;
    if (slot < cnt) {
      int j = rows[start + slot];
      if (j != i) {
        float s = S[(size_t)i * MAXG + slot];
        sum += logf(s + D[i] + EPSf) - logf(s);
      }
    }
  }
  sum = wave_reduce_sum64(sum);
  __shared__ float part[4];
  int lane = t & 63, wid = t >> 6;
  if (lane == 0) part[wid] = sum;
  __syncthreads();
  if (t == 0) partials[blockIdx.x] = part[0] + part[1] + part[2] + part[3];
}

// Pass B (fallback): recompute dots for same-label pairs
__global__ __launch_bounds__(256) void k_loss(const float* __restrict__ x,
    const float* __restrict__ invn, const int* __restrict__ y,
    const int* __restrict__ offs, const int* __restrict__ rows,
    const float* __restrict__ D, float* __restrict__ accum, int n, int d) {
  int i = blockIdx.x;
  int t = threadIdx.x, lane = t & 63, wid = t >> 6;
  __shared__ float4 xi4[256];
  __shared__ float wpart[4];

  const float4* xr = (const float4*)(x + (size_t)i * d);
  for (int q = t; q < d / 4; q += 256) xi4[q] = xr[q];
  __syncthreads();

  int g = y[i];
  int start = offs[g], end = offs[g + 1];
  float invi = invn[i];
  float Di = D[i];
  float wsum = 0.f;

  for (int idx = start + wid; idx < end; idx += 4) {
    int j = rows[idx];
    if (j == i) continue;
    const float4* xj = (const float4*)(x + (size_t)j * d);
    float acc = 0.f;
#pragma unroll 4
    for (int q = 0; q < d / 256; ++q) {
      float4 vj = xj[lane + 64 * q];
      float4 vi = xi4[lane + 64 * q];
      acc = fmaf(vj.x, vi.x, acc);
      acc = fmaf(vj.y, vi.y, acc);
      acc = fmaf(vj.z, vi.z, acc);
      acc = fmaf(vj.w, vi.w, acc);
    }
    acc = wave_reduce_sum64(acc);
    if (lane == 0) {
      float sim = acc * invi * invn[j];
      sim = fminf(fmaxf(sim, -1.0f + EPSf), 1.0f - EPSf);
      float s = fminf(expf(sim * T_INV), 1e10f);
      wsum += logf(s + Di + EPSf) - logf(s);
    }
  }

  if (lane == 0) wpart[wid] = wsum;
  __syncthreads();
  if (t == 0) atomicAdd(accum, wpart[0] + wpart[1] + wpart[2] + wpart[3]);
}

// Final reduce: sums `cnt` partials, writes out/(2n).
__global__ __launch_bounds__(256) void k_final(const float* __restrict__ partials,
    int cnt, float* __restrict__ out, int out_size, int n) {
  int t = threadIdx.x;
  float s = 0.f;
  for (int i = t; i < cnt; i += 256) s += partials[i];
  s = wave_reduce_sum64(s);
  __shared__ float part[4];
  int lane = t & 63, wid = t >> 6;
  if (lane == 0) part[wid] = s;
  __syncthreads();
  if (t == 0) {
    float v = part[0] + part[1] + part[2] + part[3];
    for (int k = 0; k < out_size; ++k) out[k] = v / (2.0f * n);
  }
}

extern "C" void kernel_launch(void* const* d_in, const int* in_sizes, int n_in,
                              void* d_out, int out_size, void* d_ws, size_t ws_size,
                              hipStream_t stream) {
  const float* x = (const float*)d_in[0];
  const int*   y = (const int*)d_in[1];
  int n = in_sizes[1];
  int d = in_sizes[0] / n;

  char* ws = (char*)d_ws;
  float* invn     = (float*)(ws);            // 16 KB
  float* D        = (float*)(ws + 16384);    // 16 KB
  int*   offs     = (int*)(ws + 32768);      // 129 ints (pad to 2 KB)
  int*   rows     = (int*)(ws + 34816);      // 16 KB
  int*   rank     = (int*)(ws + 51200);      // 16 KB
  float* accum    = (float*)(ws + 67584);    // 4 B (pad 256 B)
  float* partials = (float*)(ws + 67840);    // LBLK floats (2 KB)
  float* S        = (float*)(ws + 69888);    // n*MAXG*4 = 2 MB
  size_t xb_off = 69888 + (size_t)n * MAXG * 4;
  xb_off = (xb_off + 255) & ~(size_t)255;
  unsigned char* xb = (unsigned char*)(ws + xb_off);   // n*d fp8 = 4 MB

  int nb = n / TS;
  bool hasS  = ws_size >= 69888 + (size_t)n * MAXG * 4;
  bool hasXb = hasS && ws_size >= xb_off + (size_t)n * d
               && (d % 128 == 0) && (n % 4 == 0);

  k_prep<<<n / 4 + 1, 256, 0, stream>>>(x, y, invn, D, hasXb ? xb : nullptr,
                                        accum, offs, rows, rank, n, d);

  if (hasXb) {
    int nblocks = nb * (nb - 1) / 2 + nb;   // off-diag first, diag last
    k_gram_ldsdma<<<nblocks, 256, 0, stream>>>(xb, invn, y, rank, D, S, n, d, nb);
  } else {
    int nblocks = nb * (nb + 1) / 2;
    k_gram_reg<<<nblocks, 256, 0, stream>>>(x, invn, y, rank, D, hasS ? S : nullptr, n, d, nb);
  }
  if (hasS) {
    k_loss2<<<LBLK, 256, 0, stream>>>(y, offs, rows, D, S, partials, n);
    k_final<<<1, 256, 0, stream>>>(partials, LBLK, (float*)d_out, out_size, n);
  } else {
    k_loss<<<n, 256, 0, stream>>>(x, invn, y, offs, rows, D, accum, n, d);
    k_final<<<1, 256, 0, stream>>>(accum, 1, (float*)d_out, out_size, n);
  }
}